// Round 6
// baseline (1704.766 us; speedup 1.0000x reference)
//
#include <hip/hip_runtime.h>
#include <hip/hip_bf16.h>

typedef unsigned short u16;
typedef unsigned int u32;
typedef __bf16 bf16x8 __attribute__((ext_vector_type(8)));
typedef float f32x4 __attribute__((ext_vector_type(4)));

#define NB 64
#define NT 128
#define NF 1024
#define NH 1024
#define NK 2048   // F+H
#define NG 4096   // 4H
#define NBH (NB * NH)

// LDS: W slice 128 KiB + zs[4][64][17] f32 + handshake word
#define W_LDS_BYTES 131072
#define ZS_BYTES (4 * 64 * 17 * 4)                     // 17408
#define SMEM_BYTES (W_LDS_BYTES + ZS_BYTES + 64)       // 148544 <= 163840

__device__ __forceinline__ u16 f2bf(float f) {
  unsigned u = __builtin_bit_cast(unsigned, f);
  u = (u + 0x7FFFu + ((u >> 16) & 1u)) >> 16;
  return (u16)u;
}
__device__ __forceinline__ float bf2f(u16 v) {
  unsigned u = ((unsigned)v) << 16;
  return __builtin_bit_cast(float, u);
}

// ---------------- prep: x fp32 -> bf16 ----------------
__global__ __launch_bounds__(256) void lstm_cvt_x(const float* __restrict__ x,
                                                  u16* __restrict__ xb) {
  int i = (blockIdx.x * 256 + threadIdx.x) * 4;
  float4 v = *reinterpret_cast<const float4*>(x + i);
  ushort4 o;
  o.x = f2bf(v.x); o.y = f2bf(v.y); o.z = f2bf(v.z); o.w = f2bf(v.w);
  *reinterpret_cast<ushort4*>(xb + i) = o;
}

// ---------------- prep: W [2048,4096] fp32 -> per-block LDS-image slices ----------------
// (verified R3-R5)  base idx: ((buf*2 + kh)*32 + ch)*512 + (slot*16 + brow)*8 + elem
__global__ __launch_bounds__(256) void lstm_prep_w(const float* __restrict__ W,
                                                   u16* __restrict__ wt_blk) {
  __shared__ float tile[32][33];
  int n0 = blockIdx.x * 32;
  int k0 = blockIdx.y * 32;
  int tc = threadIdx.x & 31;
  int tr = threadIdx.x >> 5;
#pragma unroll
  for (int i = 0; i < 4; ++i) {
    int k = tr + i * 8;
    tile[k][tc] = W[(size_t)(k0 + k) * NG + n0 + tc];
  }
  __syncthreads();
#pragma unroll
  for (int i = 0; i < 4; ++i) {
    int n = n0 + tr + i * 8;
    float wv = tile[tc][tr + i * 8];
    int k = k0 + tc;
    int g = n >> 10, col = n & 1023;
    int b = col >> 2, brow = g * 4 + (col & 3);
    int kh = k >> 10, ch = (k & 1023) >> 5;
    int slot = (k >> 3) & 3, elem = k & 7;
    size_t base = (size_t)b * 65536 + (size_t)(kh * 32 + ch) * 512
                + (size_t)(slot * 16 + brow) * 8 + elem;
    u16 hi = f2bf(wv);
    wt_blk[base] = hi;
    wt_blk[base + 32768] = f2bf(wv - bf2f(hi));
  }
}

// ---------------- persistent LSTM ----------------
// Phase 1: zx[b][t][col16][row64] = x_t @ Wx_slice + bias (fp32, block-local).
//          Wave w handles t = w + 8j. K=1024, hi/lo, 3-stage load pipeline.
// Phase 2: recurrence, h-GEMM only (K=1024). Wave w = h-cols [128w,128w+128),
//          polls its 32 producer blocks' flags. Flag publish via wave 0/1
//          LDS handshake, off the block barrier.
__global__ __launch_bounds__(512) void lstm_persist(
    const u16* __restrict__ xb, u16* __restrict__ hseq,
    const u16* __restrict__ wt_blk, const float* __restrict__ bias,
    float* __restrict__ zx, float* __restrict__ out,
    u32* __restrict__ flags) {
  extern __shared__ char smem[];
  u16* Wl = (u16*)smem;
  float (*zs)[64][17] = (float(*)[64][17])(smem + W_LDS_BYTES);
  volatile u32* hsflag = (volatile u32*)(smem + W_LDS_BYTES + ZS_BYTES);

  const int b = blockIdx.x;
  const int tid = threadIdx.x;
  const int lane = tid & 63;
  const int w = tid >> 6;

  // ---- load W slice (128 KiB) into LDS ----
  {
    const u16* src = wt_blk + (size_t)b * 65536;
#pragma unroll
    for (int it = 0; it < 16; ++it) {
      uint4 v = *reinterpret_cast<const uint4*>(src + (size_t)it * 4096 + tid * 8);
      *reinterpret_cast<uint4*>(Wl + (size_t)it * 4096 + tid * 8) = v;
    }
  }
  if (tid == 0) hsflag[0] = 0;

  const int arow = lane & 15;
  const int kfr = 8 * (lane >> 4);
  const int zn = lane & 15;
  const int mg4 = (lane >> 4) * 4;
  __syncthreads();

  // ================= phase 1: zx precompute =================
  {
    // bias (+1 for forget gate) folded in; same value for all rows
    const float bv = bias[(zn >> 2) * NH + b * 4 + (zn & 3)]
                   + ((zn >> 2) == 2 ? 1.0f : 0.0f);
#pragma unroll 1
    for (int j = 0; j < 16; ++j) {
      const int t = w + 8 * j;
      const u16* a0 = xb + (size_t)arow * NT * NF + (size_t)t * NF + kfr;
      f32x4 acc[4] = {};
      bf16x8 f0[4], f1[4], f2[4];
#pragma unroll
      for (int i = 0; i < 4; ++i)
        f0[i] = *reinterpret_cast<const bf16x8*>(a0 + (size_t)i * 16 * NT * NF);
#pragma unroll
      for (int i = 0; i < 4; ++i)
        f1[i] = *reinterpret_cast<const bf16x8*>(a0 + (size_t)i * 16 * NT * NF + 32);
#pragma unroll 4
      for (int cc = 0; cc < 32; ++cc) {
        if (cc < 30) {
#pragma unroll
          for (int i = 0; i < 4; ++i)
            f2[i] = *reinterpret_cast<const bf16x8*>(
                a0 + (size_t)i * 16 * NT * NF + (cc + 2) * 32);
        }
        const bf16x8 wh = *reinterpret_cast<const bf16x8*>(
            Wl + (size_t)cc * 512 + lane * 8);                    // kh=0 hi
        const bf16x8 wlo = *reinterpret_cast<const bf16x8*>(
            Wl + (size_t)(64 + cc) * 512 + lane * 8);             // kh=0 lo
#pragma unroll
        for (int i = 0; i < 4; ++i)
          acc[i] = __builtin_amdgcn_mfma_f32_16x16x32_bf16(f0[i], wh, acc[i], 0, 0, 0);
#pragma unroll
        for (int i = 0; i < 4; ++i)
          acc[i] = __builtin_amdgcn_mfma_f32_16x16x32_bf16(f0[i], wlo, acc[i], 0, 0, 0);
#pragma unroll
        for (int i = 0; i < 4; ++i) { f0[i] = f1[i]; f1[i] = f2[i]; }
      }
      float* zp = zx + ((size_t)b * NT + t) * 1024 + zn * 64 + mg4;
#pragma unroll
      for (int i = 0; i < 4; ++i) {
        float4 v = {acc[i][0] + bv, acc[i][1] + bv, acc[i][2] + bv, acc[i][3] + bv};
        *reinterpret_cast<float4*>(zp + i * 16) = v;
      }
    }
  }
  __syncthreads();  // phase boundary (zx is block-local)

  // ================= phase 2: recurrence =================
  const int prow = tid >> 1;
  const int pc = (tid & 1) * 2;
  const int gc0 = b * 4 + pc;
  float creg[2] = {0.f, 0.f};

#pragma unroll 1
  for (int t = 0; t < NT; ++t) {
    // zx prefetch (block-local, ready since phase 1) — overlaps poll+GEMM
    float zxr[8];
    if (tid < 128) {
      const float* zp = zx + ((size_t)b * NT + t) * 1024 + prow;
#pragma unroll
      for (int g = 0; g < 4; ++g)
#pragma unroll
        for (int jj = 0; jj < 2; ++jj)
          zxr[g * 2 + jj] = zp[(g * 4 + pc + jj) * 64];
    }

    f32x4 acc[4] = {};
    if (t > 0) {
      // dataflow poll: wave w's h-cols come from blocks [32w, 32w+32)
      const u32* fp = flags + (size_t)t * 256 + 32 * w + (lane & 31);
      u32 v;
      do {
        v = __hip_atomic_load(fp, __ATOMIC_RELAXED, __HIP_MEMORY_SCOPE_AGENT);
      } while (!__all(v != 0));
      const u16* h0 = hseq + (size_t)t * NBH + (size_t)arow * NH + 128 * w + kfr;
      bf16x8 hf[4][4];
#pragma unroll
      for (int cc = 0; cc < 4; ++cc)
#pragma unroll
        for (int i = 0; i < 4; ++i)
          hf[cc][i] = *reinterpret_cast<const bf16x8*>(
              h0 + (size_t)i * 16 * NH + cc * 32);
      __builtin_amdgcn_s_setprio(1);
#pragma unroll
      for (int cc = 0; cc < 4; ++cc) {
        const int ch = w * 4 + cc;
        const bf16x8 wh = *reinterpret_cast<const bf16x8*>(
            Wl + (size_t)(32 + ch) * 512 + lane * 8);             // kh=1 hi
        const bf16x8 wlo = *reinterpret_cast<const bf16x8*>(
            Wl + (size_t)(96 + ch) * 512 + lane * 8);             // kh=1 lo
#pragma unroll
        for (int i = 0; i < 4; ++i)
          acc[i] = __builtin_amdgcn_mfma_f32_16x16x32_bf16(hf[cc][i], wh, acc[i], 0, 0, 0);
#pragma unroll
        for (int i = 0; i < 4; ++i)
          acc[i] = __builtin_amdgcn_mfma_f32_16x16x32_bf16(hf[cc][i], wlo, acc[i], 0, 0, 0);
      }
      __builtin_amdgcn_s_setprio(0);
    }

    __syncthreads();  // sync1: previous step's pointwise (and tail) done -> zs free
    if (w < 4) {
#pragma unroll
      for (int i = 0; i < 4; ++i)
#pragma unroll
        for (int r = 0; r < 4; ++r) zs[w][i * 16 + mg4 + r][zn] = acc[i][r];
    }
    __syncthreads();  // sync2
    if (w >= 4) {
#pragma unroll
      for (int i = 0; i < 4; ++i)
#pragma unroll
        for (int r = 0; r < 4; ++r) zs[w - 4][i * 16 + mg4 + r][zn] += acc[i][r];
    }
    __syncthreads();  // sync3

    if (tid < 128) {
      float hn[2];
#pragma unroll
      for (int jj = 0; jj < 2; ++jj) {
        const int col = pc + jj;
        const float zi = zs[0][prow][col]      + zs[1][prow][col]      + zs[2][prow][col]      + zs[3][prow][col]      + zxr[jj];
        const float zj = zs[0][prow][4 + col]  + zs[1][prow][4 + col]  + zs[2][prow][4 + col]  + zs[3][prow][4 + col]  + zxr[2 + jj];
        const float zf = zs[0][prow][8 + col]  + zs[1][prow][8 + col]  + zs[2][prow][8 + col]  + zs[3][prow][8 + col]  + zxr[4 + jj];
        const float zo = zs[0][prow][12 + col] + zs[1][prow][12 + col] + zs[2][prow][12 + col] + zs[3][prow][12 + col] + zxr[6 + jj];
        const float si = 1.f / (1.f + __expf(-zi));
        const float tj = tanhf(zj);
        const float sf = 1.f / (1.f + __expf(-zf));  // forget bias folded into zx
        const float so = 1.f / (1.f + __expf(-zo));
        const float cn = creg[jj] * sf + si * tj;
        hn[jj] = tanhf(cn) * so;
        creg[jj] = cn;
      }
      float2 ov = {hn[0], hn[1]};
      *reinterpret_cast<float2*>(out + ((size_t)prow * NT + t) * NH + gc0) = ov;
      if (t < NT - 1) {
        u32 hv = (u32)f2bf(hn[0]) | ((u32)f2bf(hn[1]) << 16);
        __hip_atomic_store(
            reinterpret_cast<u32*>(hseq + (size_t)(t + 1) * NBH + (size_t)prow * NH + gc0),
            hv, __ATOMIC_RELAXED, __HIP_MEMORY_SCOPE_AGENT);
      }
    }
    // flag publish: off the block barrier; waves 2-7 proceed to next poll
    if (t < NT - 1) {
      if (tid < 128) asm volatile("s_waitcnt vmcnt(0)" ::: "memory");  // waves 0-1
      if (tid == 64) hsflag[0] = (u32)(t + 1);     // wave 1 stores done
      if (tid == 0) {
        while (hsflag[0] != (u32)(t + 1)) {}       // wait wave 1
        __hip_atomic_store(&flags[(size_t)(t + 1) * 256 + b], 1u,
                           __ATOMIC_RELAXED, __HIP_MEMORY_SCOPE_AGENT);
      }
    }
  }
}

extern "C" void kernel_launch(void* const* d_in, const int* in_sizes, int n_in,
                              void* d_out, int out_size, void* d_ws, size_t ws_size,
                              hipStream_t stream) {
  const float* x = (const float*)d_in[0];
  const float* W = (const float*)d_in[1];
  const float* bias = (const float*)d_in[2];
  float* out = (float*)d_out;

  char* ws = (char*)d_ws;
  u16* xb = (u16*)(ws);                            // 16 MiB
  u16* wt_blk = (u16*)(ws + 16777216);             // 32 MiB
  u16* hseq = (u16*)(ws + 50331648);               // 16 MiB
  u32* flags = (u32*)(ws + 67108864);              // 128 KiB
  float* zx = (float*)(ws + 67239936);             // 128 MiB  (total ~192.2 MiB)

  hipMemsetAsync(hseq, 0, NBH * sizeof(u16), stream);            // h_0 = 0
  hipMemsetAsync(flags, 0, NT * 256 * sizeof(u32), stream);      // per-replay

  lstm_cvt_x<<<(NB * NT * NF) / (256 * 4), 256, 0, stream>>>(x, xb);
  lstm_prep_w<<<dim3(NG / 32, NK / 32), 256, 0, stream>>>(W, wt_blk);

  hipFuncSetAttribute((const void*)lstm_persist,
                      hipFuncAttributeMaxDynamicSharedMemorySize, SMEM_BYTES);

  void* args[] = {(void*)&xb, (void*)&hseq, (void*)&wt_blk, (void*)&bias,
                  (void*)&zx, (void*)&out, (void*)&flags};
  hipLaunchCooperativeKernel((void*)lstm_persist, dim3(256), dim3(512), args,
                             SMEM_BYTES, stream);
}